// Round 1
// baseline (146.880 us; speedup 1.0000x reference)
//
#include <hip/hip_runtime.h>

// StructNConv2D_d_with_s — fused spatial (3x3) + channel (16x16) normalized conv.
// Shapes: d,cd: (4,16,256,256) f32; s_prod_roll: (4,16,9,256,256) f32;
// spatial_weight: (16,1,9,1,1); channel_weight: (16,16,1,1).
// Outputs concatenated: d_out (4,16,256,256) then cd_out (4,16,256,256).
// STRIDE=1 -> devalue_conf = 1.

#define NB 4
#define NC 16
#define NH 256
#define NW 256
#define NK 9
#define HW (NH * NW)

static constexpr float kEPS = 1e-20f;

__global__ __launch_bounds__(256) void structnconv_fused(
    const float* __restrict__ g_d,
    const float* __restrict__ g_cd,
    const float* __restrict__ g_sp,   // s_prod_roll
    const float* __restrict__ g_sw,   // spatial_weight (16*9)
    const float* __restrict__ g_cw,   // channel_weight (16*16)
    float* __restrict__ g_dout,
    float* __restrict__ g_cdout)
{
    __shared__ float lds_sw[NC * NK];
    __shared__ float lds_cw[NC * NC];
    __shared__ float lds_part[8];

    const int t = threadIdx.x;

    // Stage weights in LDS; reduce their global sums (block-redundant, cheap).
    float v1 = (t < NC * NK) ? g_sw[t] : 0.f;
    float v2 = (t < NC * NC) ? g_cw[t] : 0.f;
    if (t < NC * NK) lds_sw[t] = v1;
    if (t < NC * NC) lds_cw[t] = v2;
    #pragma unroll
    for (int off = 32; off > 0; off >>= 1) {
        v1 += __shfl_down(v1, off);
        v2 += __shfl_down(v2, off);
    }
    if ((t & 63) == 0) {
        lds_part[t >> 6]     = v1;
        lds_part[4 + (t >> 6)] = v2;
    }
    __syncthreads();
    const float inv_sw_sum =
        1.f / (lds_part[0] + lds_part[1] + lds_part[2] + lds_part[3] + kEPS);
    const float inv_cw_sum =
        1.f / (lds_part[4] + lds_part[5] + lds_part[6] + lds_part[7] + kEPS);

    // One thread per output pixel (b,h,w); handles all 16 channels.
    const int idx = blockIdx.x * 256 + t;
    const int w = idx & (NW - 1);
    const int h = (idx >> 8) & (NH - 1);
    const int b = idx >> 16;

    float d_sp[NC];   // d_spatial per channel
    float cd_sp[NC];  // cd_spatial per channel
    float pd[NC];     // cd_spatial * d_spatial

    #pragma unroll
    for (int c = 0; c < NC; ++c) {
        const float* dbc  = g_d  + (size_t)(b * NC + c) * HW;
        const float* cdbc = g_cd + (size_t)(b * NC + c) * HW;
        const float* spb  = g_sp + ((size_t)(b * NC + c) * NK) * HW + h * NW + w;
        float nom = 0.f, den = 0.f;
        #pragma unroll
        for (int k = 0; k < NK; ++k) {
            const int di = k / 3 - 1, dj = k % 3 - 1;
            const int hh = h + di, ww = w + dj;
            float dv = 0.f, cdv = 0.f;
            if ((unsigned)hh < (unsigned)NH && (unsigned)ww < (unsigned)NW) {
                const int off = hh * NW + ww;
                dv  = dbc[off];
                cdv = cdbc[off];
            }
            const float spv = spb[k * HW];       // s_prod_roll[b,c,k,h,w]
            const float cdp = cdv * spv;         // cd_prop
            const float wck = lds_sw[c * NK + k];
            nom = fmaf(cdp * dv, wck, nom);
            den = fmaf(cdp, wck, den);
        }
        const float dsp = nom / (den + kEPS);
        d_sp[c]  = dsp;
        cd_sp[c] = den * inv_sw_sum;
        pd[c]    = cd_sp[c] * dsp;
    }

    // Channel mixing: 16x16 matvec on (cd_sp*d_sp) and cd_sp.
    const size_t outp = (size_t)b * NC * HW + (size_t)h * NW + w;
    #pragma unroll
    for (int o = 0; o < NC; ++o) {
        float n2 = 0.f, d2 = 0.f;
        #pragma unroll
        for (int c = 0; c < NC; ++c) {
            const float cwv = lds_cw[o * NC + c];
            n2 = fmaf(pd[c], cwv, n2);
            d2 = fmaf(cd_sp[c], cwv, d2);
        }
        g_dout [outp + (size_t)o * HW] = n2 / (d2 + kEPS);
        g_cdout[outp + (size_t)o * HW] = d2 * inv_cw_sum;  // devalue_conf == 1
    }
}

extern "C" void kernel_launch(void* const* d_in, const int* in_sizes, int n_in,
                              void* d_out, int out_size, void* d_ws, size_t ws_size,
                              hipStream_t stream) {
    const float* g_d  = (const float*)d_in[0];
    const float* g_cd = (const float*)d_in[1];
    // d_in[2] = s, d_in[3] = cs : unused by the reference computation.
    const float* g_sp = (const float*)d_in[4];
    const float* g_sw = (const float*)d_in[5];
    const float* g_cw = (const float*)d_in[6];

    float* g_dout  = (float*)d_out;
    float* g_cdout = g_dout + (size_t)NB * NC * HW;

    const int total_pixels = NB * NH * NW;        // 262144
    const int blocks = total_pixels / 256;        // 1024
    structnconv_fused<<<blocks, 256, 0, stream>>>(g_d, g_cd, g_sp, g_sw, g_cw,
                                                  g_dout, g_cdout);
}

// Round 2
// 54.742 us; speedup vs baseline: 2.6831x; 2.6831x over previous
//
#include <hip/hip_runtime.h>

// StructNConv2D_d_with_s — fused spatial (3x3) + channel (16x16) normalized conv.
// d,cd: (4,16,256,256) f32; s_prod_roll: (4,16,9,256,256) f32;
// spatial_weight: (16,1,9,1,1); channel_weight: (16,16,1,1).
// Outputs concatenated: d_out then cd_out, each (4,16,256,256) f32.
// STRIDE=1 -> devalue_conf = 1.
//
// R2: per-pixel channel arrays live in LDS [c][tid] (thread-private columns,
// conflict-free, no barrier needed) instead of registers; channel loop kept
// rolled. R1 had VGPR=256 + ~82MB spill writes -> 10% occupancy, 1.45 TB/s.

#define NB 4
#define NC 16
#define NH 256
#define NW 256
#define NK 9
#define HW (NH * NW)

static constexpr float kEPS = 1e-20f;

__global__ __launch_bounds__(256, 4) void structnconv_fused(
    const float* __restrict__ g_d,
    const float* __restrict__ g_cd,
    const float* __restrict__ g_sp,   // s_prod_roll
    const float* __restrict__ g_sw,   // spatial_weight (16*9)
    const float* __restrict__ g_cw,   // channel_weight (16*16)
    float* __restrict__ g_dout,
    float* __restrict__ g_cdout)
{
    __shared__ float lds_pd[NC][256];   // cd_spatial * d_spatial, per [c][tid]
    __shared__ float lds_cs[NC][256];   // cd_spatial, per [c][tid]
    __shared__ float lds_sw[NC * NK];
    __shared__ float lds_cw[NC * NC];
    __shared__ float lds_part[8];

    const int t = threadIdx.x;

    // Stage weights in LDS; reduce their global sums (block-redundant, cheap).
    float v1 = (t < NC * NK) ? g_sw[t] : 0.f;
    float v2 = (t < NC * NC) ? g_cw[t] : 0.f;
    if (t < NC * NK) lds_sw[t] = v1;
    if (t < NC * NC) lds_cw[t] = v2;
    #pragma unroll
    for (int off = 32; off > 0; off >>= 1) {
        v1 += __shfl_down(v1, off);
        v2 += __shfl_down(v2, off);
    }
    if ((t & 63) == 0) {
        lds_part[t >> 6]       = v1;
        lds_part[4 + (t >> 6)] = v2;
    }
    __syncthreads();
    const float inv_sw_sum =
        1.f / (lds_part[0] + lds_part[1] + lds_part[2] + lds_part[3] + kEPS);
    const float inv_cw_sum =
        1.f / (lds_part[4] + lds_part[5] + lds_part[6] + lds_part[7] + kEPS);

    // One thread per output pixel (b,h,w); block covers one full (b,h) row.
    const int idx = blockIdx.x * 256 + t;
    const int w = idx & (NW - 1);
    const int h = (idx >> 8) & (NH - 1);
    const int b = idx >> 16;
    const int pix = h * NW + w;

    // ---- Spatial phase: rolled over channels, results to LDS columns ----
    #pragma unroll 1
    for (int c = 0; c < NC; ++c) {
        const float* dbc  = g_d  + (size_t)(b * NC + c) * HW + pix;
        const float* cdbc = g_cd + (size_t)(b * NC + c) * HW + pix;
        const float* spb  = g_sp + ((size_t)(b * NC + c) * NK) * HW + pix;
        float nom = 0.f, den = 0.f;
        #pragma unroll
        for (int k = 0; k < NK; ++k) {
            const int di = k / 3 - 1, dj = k % 3 - 1;
            const int hh = h + di, ww = w + dj;
            float dv = 0.f, cdv = 0.f;
            if ((unsigned)hh < (unsigned)NH && (unsigned)ww < (unsigned)NW) {
                const int off = di * NW + dj;
                dv  = dbc[off];
                cdv = cdbc[off];
            }
            const float cdp = cdv * spb[k * HW];   // cd_prop
            const float wck = lds_sw[c * NK + k];
            nom = fmaf(cdp * dv, wck, nom);
            den = fmaf(cdp, wck, den);
        }
        const float dsp  = nom / (den + kEPS);
        const float cdsp = den * inv_sw_sum;
        lds_cs[c][t] = cdsp;
        lds_pd[c][t] = cdsp * dsp;
    }
    // No barrier: each thread only reads its own LDS column.

    // ---- Channel mixing: 16x16 matvec from LDS columns ----
    const size_t outp = (size_t)b * NC * HW + pix;
    #pragma unroll 1
    for (int o = 0; o < NC; ++o) {
        float n2 = 0.f, d2 = 0.f;
        #pragma unroll
        for (int c = 0; c < NC; ++c) {
            const float cwv = lds_cw[o * NC + c];
            n2 = fmaf(lds_pd[c][t], cwv, n2);
            d2 = fmaf(lds_cs[c][t], cwv, d2);
        }
        g_dout [outp + (size_t)o * HW] = n2 / (d2 + kEPS);
        g_cdout[outp + (size_t)o * HW] = d2 * inv_cw_sum;  // devalue_conf == 1
    }
}

extern "C" void kernel_launch(void* const* d_in, const int* in_sizes, int n_in,
                              void* d_out, int out_size, void* d_ws, size_t ws_size,
                              hipStream_t stream) {
    const float* g_d  = (const float*)d_in[0];
    const float* g_cd = (const float*)d_in[1];
    // d_in[2] = s, d_in[3] = cs : unused by the reference computation.
    const float* g_sp = (const float*)d_in[4];
    const float* g_sw = (const float*)d_in[5];
    const float* g_cw = (const float*)d_in[6];

    float* g_dout  = (float*)d_out;
    float* g_cdout = g_dout + (size_t)NB * NC * HW;

    const int total_pixels = NB * NH * NW;        // 262144
    const int blocks = total_pixels / 256;        // 1024
    structnconv_fused<<<blocks, 256, 0, stream>>>(g_d, g_cd, g_sp, g_sw, g_cw,
                                                  g_dout, g_cdout);
}

// Round 3
// 53.553 us; speedup vs baseline: 2.7427x; 1.0222x over previous
//
#include <hip/hip_runtime.h>

// StructNConv2D_d_with_s — fused spatial (3x3) + channel (16x16) normalized conv.
// d,cd: (4,16,256,256) f32; s_prod_roll: (4,16,9,256,256) f32;
// spatial_weight: (16,1,9,1,1); channel_weight: (16,16,1,1).
// Outputs concatenated: d_out then cd_out, each (4,16,256,256) f32.
//
// R3: channel-mix fused into the spatial c-loop via 64 statically-indexed
// register accumulators (no [c][tid] LDS arrays -> LDS 33KB->1KB, ds ops
// 800->256/thread). 2 pixels/thread with float2 loads halves VMEM instrs
// per pixel. 128-thr blocks, one (b,h) row per block, 8 blocks/CU.

#define NB 4
#define NC 16
#define NH 256
#define NW 256
#define NK 9
#define HW (NH * NW)
#define TPB 128

static constexpr float kEPS = 1e-20f;

__global__ __launch_bounds__(TPB, 4) void structnconv_fused(
    const float* __restrict__ g_d,
    const float* __restrict__ g_cd,
    const float* __restrict__ g_sp,   // s_prod_roll
    const float* __restrict__ g_sw,   // spatial_weight (16*9)
    const float* __restrict__ g_cw,   // channel_weight (16*16)
    float* __restrict__ g_dout,
    float* __restrict__ g_cdout)
{
    __shared__ float lds_sw[NC * NK];   // 144
    __shared__ float lds_cw[NC * NC];   // 256
    __shared__ float lds_part[4];

    const int t = threadIdx.x;

    // Stage weights + compute their global sums (block-redundant, tiny).
    float s1 = g_sw[t];                       // t < 128 < 144
    float s2 = g_cw[t] + g_cw[TPB + t];
    lds_sw[t] = s1;
    lds_cw[t] = g_cw[t];
    lds_cw[TPB + t] = g_cw[TPB + t];
    if (t < NC * NK - TPB) {                  // 16 tail elements of sw
        const float v = g_sw[TPB + t];
        lds_sw[TPB + t] = v;
        s1 += v;
    }
    #pragma unroll
    for (int off = 32; off > 0; off >>= 1) {
        s1 += __shfl_down(s1, off);
        s2 += __shfl_down(s2, off);
    }
    if ((t & 63) == 0) {
        lds_part[t >> 6]     = s1;
        lds_part[2 + (t >> 6)] = s2;
    }
    __syncthreads();
    const float inv_sw_sum = 1.f / (lds_part[0] + lds_part[1] + kEPS);
    const float inv_cw_sum = 1.f / (lds_part[2] + lds_part[3] + kEPS);

    // Block -> one (b, h) row; thread -> 2 consecutive pixels.
    const int b  = blockIdx.x >> 8;
    const int h  = blockIdx.x & (NH - 1);
    const int w0 = t << 1;

    float an0[NC], an1[NC], ad0[NC], ad1[NC];   // channel-mix accumulators
    #pragma unroll
    for (int o = 0; o < NC; ++o) { an0[o] = an1[o] = ad0[o] = ad1[o] = 0.f; }

    #pragma unroll 1
    for (int c = 0; c < NC; ++c) {
        const float* pdd = g_d  + (size_t)(b * NC + c) * HW + h * NW + w0;
        const float* pcc = g_cd + (size_t)(b * NC + c) * HW + h * NW + w0;
        const float* pss = g_sp + ((size_t)(b * NC + c) * NK) * HW + h * NW + w0;

        float nom0 = 0.f, nom1 = 0.f, den0 = 0.f, den1 = 0.f;
        #pragma unroll
        for (int r = 0; r < 3; ++r) {
            const int hh = h + r - 1;
            const bool rowok = (unsigned)hh < (unsigned)NH;   // uniform
            const int roff = (r - 1) * NW;
            float2 m_d = {0.f, 0.f}, m_c = {0.f, 0.f};
            float wl_d = 0.f, wr_d = 0.f, wl_c = 0.f, wr_c = 0.f;
            if (rowok) {
                m_d = *(const float2*)(pdd + roff);
                m_c = *(const float2*)(pcc + roff);
                if (w0 > 0)      { wl_d = pdd[roff - 1]; wl_c = pcc[roff - 1]; }
                if (w0 + 2 < NW) { wr_d = pdd[roff + 2]; wr_c = pcc[roff + 2]; }
            }
            const float cold[4] = {wl_d, m_d.x, m_d.y, wr_d};
            const float colc[4] = {wl_c, m_c.x, m_c.y, wr_c};
            #pragma unroll
            for (int dj = 0; dj < 3; ++dj) {
                const int k = r * 3 + dj;
                const float2 spv = *(const float2*)(pss + (size_t)k * HW);
                const float wck  = lds_sw[c * NK + k];
                const float cdp0 = colc[dj]     * spv.x;
                const float cdp1 = colc[dj + 1] * spv.y;
                nom0 = fmaf(cdp0 * cold[dj],     wck, nom0);
                den0 = fmaf(cdp0,                wck, den0);
                nom1 = fmaf(cdp1 * cold[dj + 1], wck, nom1);
                den1 = fmaf(cdp1,                wck, den1);
            }
        }
        const float dsp0 = nom0 / (den0 + kEPS);
        const float dsp1 = nom1 / (den1 + kEPS);
        const float cs0  = den0 * inv_sw_sum;
        const float cs1  = den1 * inv_sw_sum;
        const float pd0  = cs0 * dsp0;
        const float pd1  = cs1 * dsp1;

        #pragma unroll
        for (int o = 0; o < NC; ++o) {
            const float cwv = lds_cw[o * NC + c];
            an0[o] = fmaf(pd0, cwv, an0[o]);
            an1[o] = fmaf(pd1, cwv, an1[o]);
            ad0[o] = fmaf(cs0, cwv, ad0[o]);
            ad1[o] = fmaf(cs1, cwv, ad1[o]);
        }
    }

    // Epilogue: normalize + store (float2 per array per channel).
    const size_t outp = (size_t)b * NC * HW + (size_t)h * NW + w0;
    #pragma unroll
    for (int o = 0; o < NC; ++o) {
        float2 dv, cv;
        dv.x = an0[o] / (ad0[o] + kEPS);
        dv.y = an1[o] / (ad1[o] + kEPS);
        cv.x = ad0[o] * inv_cw_sum;     // devalue_conf == 1
        cv.y = ad1[o] * inv_cw_sum;
        *(float2*)(g_dout  + outp + (size_t)o * HW) = dv;
        *(float2*)(g_cdout + outp + (size_t)o * HW) = cv;
    }
}

extern "C" void kernel_launch(void* const* d_in, const int* in_sizes, int n_in,
                              void* d_out, int out_size, void* d_ws, size_t ws_size,
                              hipStream_t stream) {
    const float* g_d  = (const float*)d_in[0];
    const float* g_cd = (const float*)d_in[1];
    // d_in[2] = s, d_in[3] = cs : unused by the reference computation.
    const float* g_sp = (const float*)d_in[4];
    const float* g_sw = (const float*)d_in[5];
    const float* g_cw = (const float*)d_in[6];

    float* g_dout  = (float*)d_out;
    float* g_cdout = g_dout + (size_t)NB * NC * HW;

    const int blocks = NB * NH;   // 1024 blocks, one (b,h) row each
    structnconv_fused<<<blocks, TPB, 0, stream>>>(g_d, g_cd, g_sp, g_sw, g_cw,
                                                  g_dout, g_cdout);
}